// Round 5
// baseline (468.543 us; speedup 1.0000x reference)
//
#include <hip/hip_runtime.h>

// Problem constants
#define V_CNT   10475
#define M_A     704
#define N_A     128
#define KB      10
#define D_TOT   270336       // 704*128*3
#define ROW384  384          // 128*3 floats per m-row of a pc row
#define NCHUNK  44           // 704 / MT
#define MT      16           // m-tile in k_pcpass (24.8 KB LDS -> 5 blocks/CU)
#define LSTR    388          // LDS row stride: 388%32=4 breaks bank conflicts, %4==0 keeps float4 alignment

// ws layout (float offsets) -- ALL hot-pass outputs are p-major (contiguous per block, no atomics)
#define WS_JJ     0          // 33: Jv[3], JB[3][10]           (atomic)
#define WS_CMEAN  64         // 128                            (atomic)
#define WS_MC     192        // 384                            (atomic)
#define WS_V2C    576        // 3*128   V2c[c][p]              (written by k_red)
#define WS_SASUM  960        // 64*3                           (written by k_pre)
#define WS_GWS    1152       // 64*128  gamma pre-correction   (written by k_gamma)
#define WS_U2     9344       // 128*384  U2[pid][nc]           (written by k_red)
#define WS_UPART  58496      // 44*128*384 = 2162688 Upart[chunk][pid][nc]
#define WS_V2P    2221184    // 128*2112 V2p[pid][mc]
#define WS_XT     2491520    // 2496*64  Xt[e][b]: rows 0..383 obj, 384.. sa0
#define WS_TOTAL  2651264    // floats (10.6 MB)
#define WS_ZEROF  1152       // zero only the atomic targets (JJ, cmean, Mc)

#define NJ_BLK 28
#define NM_BLK 88
#define NP_BLK 64

// ---------------------------------------------------------------- K1: fused precompute
// blocks [0,28): J-reduce; [28,116): Mc-reduce; [116,180): per-b prep (obj + sa0 -> Xt, saSum)
__global__ __launch_bounds__(384) void k_pre(
    const float* __restrict__ Jr, const float* __restrict__ vt,
    const float* __restrict__ sd, const float* __restrict__ mean,
    const float* __restrict__ betas, const float* __restrict__ rot,
    const float* __restrict__ trans, const float* __restrict__ org,
    const int* __restrict__ anch,
    float* __restrict__ JJ, float* __restrict__ Mc,
    float* __restrict__ Xt, float* __restrict__ saSum) {
  __shared__ float orgL[384];
  __shared__ float red[384];
  __shared__ float small[24];  // 0..9 betas, 10..18 rot, 19..21 trans
  const int blk = blockIdx.x, t = threadIdx.x;

  if (blk < NJ_BLK) {
    float acc[33];
#pragma unroll
    for (int i = 0; i < 33; ++i) acc[i] = 0.f;
    int v = blk * 384 + t;
    if (v < V_CNT) {
      float jr = Jr[v];
#pragma unroll
      for (int c = 0; c < 3; ++c) {
        acc[c] += jr * vt[v * 3 + c];
        const float* sp = sd + ((size_t)v * 3 + c) * KB;
#pragma unroll
        for (int k = 0; k < KB; ++k) acc[3 + c * KB + k] += jr * sp[k];
      }
    }
#pragma unroll
    for (int i = 0; i < 33; ++i) {
      float x = acc[i];
      for (int off = 32; off > 0; off >>= 1) x += __shfl_down(x, off);
      if ((t & 63) == 0) atomicAdd(&JJ[i], x);
    }
  } else if (blk < NJ_BLK + NM_BLK) {
    int j = blk - NJ_BLK;
    float a = 0.f;
#pragma unroll
    for (int mi = 0; mi < 8; ++mi)
      a += mean[(size_t)(j * 8 + mi) * ROW384 + t];
    atomicAdd(&Mc[t], a);
  } else {
    const int b = blk - (NJ_BLK + NM_BLK);
    if (t < 10) small[t] = betas[b * 10 + t];
    else if (t >= 10 && t < 19) small[t] = rot[b * 9 + (t - 10)];
    else if (t >= 19 && t < 22) small[t] = trans[b * 3 + (t - 19)];
    orgL[t] = org[(size_t)b * 384 + t];
    __syncthreads();
    // obj[n,d] -> Xt rows [0,384)
    {
      int n = t / 3, d = t % 3;
      Xt[(size_t)t * 64 + b] =
          orgL[n * 3 + 0] * small[10 + d * 3 + 0] +
          orgL[n * 3 + 1] * small[10 + d * 3 + 1] +
          orgL[n * 3 + 2] * small[10 + d * 3 + 2] + small[19 + d];
    }
    // sa0[m,c] = vt + betas.sd (no J0) -> Xt rows [384,2496)
    float ps = 0.f;  // c = e%3 fixed per thread (384%3==0)
    for (int e = t; e < 2112; e += 384) {
      int m = e / 3, c = e - m * 3;
      int a = anch[m];
      const float* sp = sd + ((size_t)a * 3 + c) * KB;
      float val = vt[a * 3 + c];
#pragma unroll
      for (int k = 0; k < KB; ++k) val += small[k] * sp[k];
      Xt[(size_t)(384 + e) * 64 + b] = val;
      ps += val;
    }
    red[t] = ps;
    __syncthreads();
    if (t < 3) {
      float s = 0.f;
#pragma unroll 8
      for (int j = 0; j < 128; ++j) s += red[t + 3 * j];
      saSum[b * 3 + t] = s;
    }
  }
}

// ---------------------------------------------------------------- K2: single pass over pca_components
// block = (chunk, pid): 16x384 tile of pc row pid.
// Outputs are CONTIGUOUS per-block (no scattered atomics -- r4's WRITE_SIZE lesson):
//   Upart[chunk][pid][0:384]  = column sums over the 16 m's   (1536 B burst)
//   V2p[pid][m0*3 : m0*3+48]  = row sums over n               (192 B burst, exclusive)
//   cmean[pid]               += tile . mean-tile              (1 atomic/block)
__global__ __launch_bounds__(384) void k_pcpass(
    const float* __restrict__ pc, const float* __restrict__ mean,
    float* __restrict__ Upart, float* __restrict__ V2p,
    float* __restrict__ cmean) {
  __shared__ float tile[MT * LSTR];  // 24,832 B
  __shared__ float red[384];
  __shared__ float cred[6];
  const int t = threadIdx.x;
  const int pid = blockIdx.x & 127;
  const int chunk = blockIdx.x >> 7;  // 0..43
  const int m0 = chunk * MT;
  const float* row = pc + (size_t)pid * D_TOT + (size_t)m0 * ROW384;
  const float* mrow = mean + (size_t)m0 * ROW384;

  float cm = 0.f;
#pragma unroll
  for (int i = 0; i < 4; ++i) {
    int f = 1536 * i + 4 * t;
    float4 pv = *(const float4*)(row + f);
    float4 mv = *(const float4*)(mrow + f);
    cm += pv.x * mv.x + pv.y * mv.y + pv.z * mv.z + pv.w * mv.w;
    int m_l = 4 * i + t / 96;
    int col = (t % 96) * 4;
    *(float4*)(&tile[m_l * LSTR + col]) = pv;
  }
  __syncthreads();  // S1

  // U partial: fixed (n,c)=t, sum over 16 m -> contiguous store
  {
    float u = 0.f;
#pragma unroll
    for (int m = 0; m < MT; ++m) u += tile[m * LSTR + t];
    Upart[((size_t)chunk * 128 + pid) * 384 + t] = u;
  }
  // V partial: t = grp*48 + (m_l*3+c), grp 0..7 each sums 16 n's
  {
    int grp = t / 48, mc = t % 48, m_l = mc / 3, c = mc % 3;
    const float* tp = &tile[m_l * LSTR + c];
    float vsp = 0.f;
#pragma unroll 8
    for (int j = 0; j < 16; ++j) vsp += tp[(grp * 16 + j) * 3];
    red[t] = vsp;
  }
  // cmean wave-reduce
  {
    float x = cm;
    for (int off = 32; off > 0; off >>= 1) x += __shfl_down(x, off);
    if ((t & 63) == 0) cred[t >> 6] = x;
  }
  __syncthreads();  // S2
  if (t < 48) {
    float vs = 0.f;
#pragma unroll
    for (int g = 0; g < 8; ++g) vs += red[g * 48 + t];
    V2p[(size_t)pid * 2112 + m0 * 3 + t] = vs;  // contiguous, exclusive
  }
  if (t == 0) {
    float s = cred[0] + cred[1] + cred[2] + cred[3] + cred[4] + cred[5];
    atomicAdd(&cmean[pid], s);
  }
}

// ---------------------------------------------------------------- K2b: reduce Upart over chunks; V2c
__global__ __launch_bounds__(384) void k_red(
    const float* __restrict__ Upart, const float* __restrict__ V2p,
    float* __restrict__ U2, float* __restrict__ V2c) {
  __shared__ float red[384];
  const int pid = blockIdx.x, t = threadIdx.x;
  float u = 0.f;
  for (int c = 0; c < NCHUNK; ++c)
    u += Upart[((size_t)c * 128 + pid) * 384 + t];
  U2[(size_t)pid * 384 + t] = u;
  // V2c[c][pid] = sum_m V2p[pid][m*3+c]; thread t covers indices t+384j (c = t%3 fixed)
  float s = 0.f;
  const float* vr = V2p + (size_t)pid * 2112;
#pragma unroll
  for (int j = 0; j < 6; ++j) {
    int idx = t + 384 * j;
    if (idx < 2112) s += vr[idx];
  }
  red[t] = s;
  __syncthreads();
  if (t < 3) {
    float acc = 0.f;
#pragma unroll 8
    for (int j = 0; j < 128; ++j) acc += red[t + 3 * j];
    V2c[t * 128 + pid] = acc;
  }
}

// ---------------------------------------------------------------- K3: gamma, block per p (no atomics)
// gamma_pre[b][p] = sum_{e<384} Xt[e][b]*U2[p][e] - sum_{e>=384} Xt[e][b]*V2p[p][e-384]
__global__ __launch_bounds__(256) void k_gamma(
    const float* __restrict__ Xt, const float* __restrict__ U2,
    const float* __restrict__ V2p, float* __restrict__ gWS) {
  __shared__ float red[4][64];
  const int p = blockIdx.x, t = threadIdx.x;
  const int b = t & 63, g = t >> 6;  // wave g handles e range [g*624, (g+1)*624)
  const float* Ur = U2 + (size_t)p * 384;
  const float* Vr = V2p + (size_t)p * 2112;
  float s = 0.f;
  const int e0 = g * 624, e1 = e0 + 624;
  int e = e0;
  const int eb = (e1 < 384) ? e1 : 384;
  for (; e < eb; ++e) s += Xt[(size_t)e * 64 + b] * Ur[e];           // wave-uniform Ur bcast
  for (; e < e1; ++e) s -= Xt[(size_t)e * 64 + b] * Vr[e - 384];
  red[g][b] = s;
  __syncthreads();
  if (t < 64)
    gWS[(size_t)t * 128 + p] = red[0][t] + red[1][t] + red[2][t] + red[3][t];
}

// ---------------------------------------------------------------- 3x3 SVD -> rotation (Kabsch w/ reflection fix)
__device__ inline double det3(const double A[3][3]) {
  return A[0][0] * (A[1][1] * A[2][2] - A[1][2] * A[2][1])
       - A[0][1] * (A[1][0] * A[2][2] - A[1][2] * A[2][0])
       + A[0][2] * (A[1][0] * A[2][1] - A[1][1] * A[2][0]);
}

__device__ void svd3_rotation(const float* S, float* Rout) {
  double M[3][3], B[3][3], Vv[3][3];
  for (int i = 0; i < 3; ++i)
    for (int j = 0; j < 3; ++j) M[i][j] = (double)S[i * 3 + j];
  for (int i = 0; i < 3; ++i)
    for (int j = 0; j < 3; ++j) {
      double a = 0;
      for (int k = 0; k < 3; ++k) a += M[k][i] * M[k][j];
      B[i][j] = a;
    }
  for (int i = 0; i < 3; ++i)
    for (int j = 0; j < 3; ++j) Vv[i][j] = (i == j) ? 1.0 : 0.0;
  const int PP[3] = {0, 0, 1}, QQ[3] = {1, 2, 2};
  for (int sweep = 0; sweep < 25; ++sweep) {
    double off = B[0][1] * B[0][1] + B[0][2] * B[0][2] + B[1][2] * B[1][2];
    double dg = B[0][0] * B[0][0] + B[1][1] * B[1][1] + B[2][2] * B[2][2];
    if (off <= 1e-28 * (dg + 1e-300)) break;
    for (int pr = 0; pr < 3; ++pr) {
      int p = PP[pr], q = QQ[pr];
      double apq = B[p][q];
      if (apq == 0.0) continue;
      double dd = (B[p][p] - B[q][q]) / (2.0 * apq);
      double tt = 1.0 / (fabs(dd) + sqrt(dd * dd + 1.0));
      if (dd < 0.0) tt = -tt;
      double cc = 1.0 / sqrt(tt * tt + 1.0), ss = tt * cc;
      B[p][p] += tt * apq;
      B[q][q] -= tt * apq;
      B[p][q] = B[q][p] = 0.0;
      int k = 3 - p - q;
      double Bkp = cc * B[k][p] + ss * B[k][q];
      double Bkq = -ss * B[k][p] + cc * B[k][q];
      B[k][p] = B[p][k] = Bkp;
      B[k][q] = B[q][k] = Bkq;
      for (int i = 0; i < 3; ++i) {
        double vip = cc * Vv[i][p] + ss * Vv[i][q];
        double viq = -ss * Vv[i][p] + cc * Vv[i][q];
        Vv[i][p] = vip;
        Vv[i][q] = viq;
      }
    }
  }
  double lam[3] = {B[0][0], B[1][1], B[2][2]};
  int o0 = 0, o1 = 1, o2 = 2, tp;
  if (lam[o0] < lam[o1]) { tp = o0; o0 = o1; o1 = tp; }
  if (lam[o0] < lam[o2]) { tp = o0; o0 = o2; o2 = tp; }
  if (lam[o1] < lam[o2]) { tp = o1; o1 = o2; o2 = tp; }
  int ord[3] = {o0, o1, o2};
  double sv[3], U[3][3], Vs[3][3];
  for (int j = 0; j < 3; ++j) {
    double l = lam[ord[j]];
    sv[j] = l > 0.0 ? sqrt(l) : 0.0;
    for (int i = 0; i < 3; ++i) Vs[i][j] = Vv[i][ord[j]];
  }
  for (int j = 0; j < 3; ++j) {
    double vx = Vs[0][j], vy = Vs[1][j], vz = Vs[2][j];
    double ux = M[0][0] * vx + M[0][1] * vy + M[0][2] * vz;
    double uy = M[1][0] * vx + M[1][1] * vy + M[1][2] * vz;
    double uz = M[2][0] * vx + M[2][1] * vy + M[2][2] * vz;
    double sj = sv[j];
    if (sj > 1e-12 * (sv[0] + 1e-300)) {
      U[0][j] = ux / sj; U[1][j] = uy / sj; U[2][j] = uz / sj;
    } else if (j == 2) {
      double cx = U[1][0] * U[2][1] - U[2][0] * U[1][1];
      double cy = U[2][0] * U[0][1] - U[0][0] * U[2][1];
      double cz = U[0][0] * U[1][1] - U[1][0] * U[0][1];
      double nn = sqrt(cx * cx + cy * cy + cz * cz);
      if (nn < 1e-300) { cx = 0; cy = 0; cz = 1; nn = 1; }
      U[0][2] = cx / nn; U[1][2] = cy / nn; U[2][2] = cz / nn;
    } else {
      U[0][j] = (j == 0) ? 1.0 : 0.0;
      U[1][j] = (j == 1) ? 1.0 : 0.0;
      U[2][j] = 0.0;
    }
  }
  double dsgn = (det3(U) * det3(Vs)) < 0.0 ? -1.0 : 1.0;
  for (int i = 0; i < 3; ++i)
    for (int j = 0; j < 3; ++j)
      Rout[i * 3 + j] = (float)(U[i][0] * Vs[j][0] + U[i][1] * Vs[j][1] +
                                dsgn * U[i][2] * Vs[j][2]);
}

// ---------------------------------------------------------------- K4: finalize per batch
__global__ __launch_bounds__(384) void k_finish(
    const float* __restrict__ betas, const float* __restrict__ org,
    const float* __restrict__ JJ, const float* __restrict__ cmean,
    const float* __restrict__ Mc, const float* __restrict__ V2c,
    const float* __restrict__ saSum, const float* __restrict__ gWS,
    const float* __restrict__ U2, float* __restrict__ out) {
  const int b = blockIdx.x, t = threadIdx.x;
  __shared__ float orgL[384], A[384], gammaL[128];
  __shared__ float betasL[10], J0L[3], cQ[3], smat[9], RL[9];

  if (t < 10) betasL[t] = betas[b * 10 + t];
  orgL[t] = org[(size_t)b * 384 + t];
  __syncthreads();
  if (t < 3) {
    float j0 = JJ[t];
#pragma unroll
    for (int k = 0; k < KB; ++k) j0 += betasL[k] * JJ[3 + t * KB + k];
    J0L[t] = j0;
    float s = 0.f;
    for (int n = 0; n < N_A; ++n) s += orgL[n * 3 + t];
    cQ[t] = s * (1.f / 128.f);
  }
  __syncthreads();

  // gamma finalize: + J0.V2c (restores the -J0 part of sa) - cmean
  if (t < 128) {
    float g = gWS[b * 128 + t] + J0L[0] * V2c[t] + J0L[1] * V2c[128 + t] +
              J0L[2] * V2c[256 + t] - cmean[t];
    gammaL[t] = g;
    out[b * 128 + t] = g;  // output 0
  }
  __syncthreads();

  // A[n,c] = Mc + sum_p gamma[p]*U2[p][nc]  (coalesced over t)
  {
    float gs = 0.f;
    for (int p = 0; p < 128; ++p) gs += gammaL[p] * U2[(size_t)p * 384 + t];
    A[t] = Mc[t] + gs;
  }
  __syncthreads();

  if (t < 9) {
    int c = t / 3, d = t % 3;
    float s = 0.f, cq = cQ[d];
    for (int n = 0; n < N_A; ++n) s += A[n * 3 + c] * (orgL[n * 3 + d] - cq);
    smat[t] = s;
  }
  __syncthreads();
  if (t == 0) svd3_rotation(smat, RL);
  __syncthreads();
  if (t < 9) out[8192 + b * 9 + t] = RL[t];  // output 1
  if (t < 3) {
    float s2 = 0.f;
    for (int n = 0; n < N_A; ++n) s2 += A[n * 3 + t];
    float meanP = saSum[b * 3 + t] * (1.f / 704.f) - J0L[t] + s2 * (1.f / 90112.f);
    float rq = RL[t * 3 + 0] * cQ[0] + RL[t * 3 + 1] * cQ[1] + RL[t * 3 + 2] * cQ[2];
    out[8768 + b * 3 + t] = meanP - rq;  // output 2
  }
}

// ----------------------------------------------------------------
extern "C" void kernel_launch(void* const* d_in, const int* in_sizes, int n_in,
                              void* d_out, int out_size, void* d_ws, size_t ws_size,
                              hipStream_t stream) {
  const float* betas = (const float*)d_in[0];
  const float* rot   = (const float*)d_in[1];
  const float* trans = (const float*)d_in[2];
  const float* org   = (const float*)d_in[3];
  const float* vt    = (const float*)d_in[4];
  const float* sd    = (const float*)d_in[5];
  const float* Jr    = (const float*)d_in[6];
  const float* mean  = (const float*)d_in[7];
  const float* pc    = (const float*)d_in[8];
  const int*   anch  = (const int*)d_in[9];
  float* out = (float*)d_out;
  float* ws  = (float*)d_ws;
  if (ws_size < (size_t)WS_TOTAL * sizeof(float)) return;  // need ~10.6 MB scratch

  float* JJ    = ws + WS_JJ;
  float* cmean = ws + WS_CMEAN;
  float* Mc    = ws + WS_MC;
  float* V2c   = ws + WS_V2C;
  float* saSum = ws + WS_SASUM;
  float* gWS   = ws + WS_GWS;
  float* U2    = ws + WS_U2;
  float* Upart = ws + WS_UPART;
  float* V2p   = ws + WS_V2P;
  float* Xt    = ws + WS_XT;

  hipMemsetAsync(ws, 0, (size_t)WS_ZEROF * sizeof(float), stream);
  k_pre<<<NJ_BLK + NM_BLK + NP_BLK, 384, 0, stream>>>(
      Jr, vt, sd, mean, betas, rot, trans, org, anch, JJ, Mc, Xt, saSum);
  k_pcpass<<<NCHUNK * 128, 384, 0, stream>>>(pc, mean, Upart, V2p, cmean);
  k_red<<<128, 384, 0, stream>>>(Upart, V2p, U2, V2c);
  k_gamma<<<128, 256, 0, stream>>>(Xt, U2, V2p, gWS);
  k_finish<<<64, 384, 0, stream>>>(betas, org, JJ, cmean, Mc, V2c, saSum, gWS,
                                   U2, out);
}

// Round 6
// 305.551 us; speedup vs baseline: 1.5334x; 1.5334x over previous
//
#include <hip/hip_runtime.h>

// Problem constants
#define V_CNT   10475
#define M_A     704
#define N_A     128
#define KB      10
#define D_TOT   270336       // 704*128*3
#define ROW384  384          // 128*3 floats per m-row of a pc row
#define NCHUNK  44           // 704 / MT
#define MT      16           // m-tile in k_pcpass (24.8 KB LDS -> 5 blocks/CU)
#define LSTR    388          // LDS row stride: 388%32=4 breaks bank conflicts, %4==0 keeps float4 alignment

// ws layout (float offsets) -- hot-pass outputs contiguous per block (no scattered atomics)
#define WS_JJ     0          // 33: Jv[3], JB[3][10]           (atomic)
#define WS_CMEAN  64         // 128                            (atomic)
#define WS_MC     192        // 384                            (atomic)
#define WS_V2C    576        // 3*128   V2c[c][p]              (k_red)
#define WS_SASUM  960        // 64*3                           (k_pre)
#define WS_GWS    1152       // 64*128  gamma pre-correction   (k_gamma)
#define WS_X      9344       // 64*2496 X[b][e]: [obj(384); sa0(2112)]  (k_pre, b-major)
#define WS_WP     169088     // 128*2496 Wp[p][e]: [0,384)=U row (k_red), [384,2496)=-V2 (k_pcpass)
#define WS_UPART  488576     // 44*128*384 = 2162688 Upart[chunk][pid][nc]
#define WS_TOTAL  2651264    // floats (10.6 MB)
#define WS_ZEROF  1152       // zero only the atomic targets (JJ, cmean, Mc)

#define NJ_BLK 28
#define NM_BLK 88
#define NP_BLK 64

// ---------------------------------------------------------------- K1: fused precompute
// blocks [0,28): J-reduce; [28,116): Mc-reduce; [116,180): per-b prep (obj + sa0 -> X, saSum)
__global__ __launch_bounds__(384) void k_pre(
    const float* __restrict__ Jr, const float* __restrict__ vt,
    const float* __restrict__ sd, const float* __restrict__ mean,
    const float* __restrict__ betas, const float* __restrict__ rot,
    const float* __restrict__ trans, const float* __restrict__ org,
    const int* __restrict__ anch,
    float* __restrict__ JJ, float* __restrict__ Mc,
    float* __restrict__ X, float* __restrict__ saSum) {
  __shared__ float orgL[384];
  __shared__ float red[384];
  __shared__ float small[24];  // 0..9 betas, 10..18 rot, 19..21 trans
  const int blk = blockIdx.x, t = threadIdx.x;

  if (blk < NJ_BLK) {
    float acc[33];
#pragma unroll
    for (int i = 0; i < 33; ++i) acc[i] = 0.f;
    int v = blk * 384 + t;
    if (v < V_CNT) {
      float jr = Jr[v];
#pragma unroll
      for (int c = 0; c < 3; ++c) {
        acc[c] += jr * vt[v * 3 + c];
        const float* sp = sd + ((size_t)v * 3 + c) * KB;
#pragma unroll
        for (int k = 0; k < KB; ++k) acc[3 + c * KB + k] += jr * sp[k];
      }
    }
#pragma unroll
    for (int i = 0; i < 33; ++i) {
      float x = acc[i];
      for (int off = 32; off > 0; off >>= 1) x += __shfl_down(x, off);
      if ((t & 63) == 0) atomicAdd(&JJ[i], x);
    }
  } else if (blk < NJ_BLK + NM_BLK) {
    int j = blk - NJ_BLK;
    float a = 0.f;
#pragma unroll
    for (int mi = 0; mi < 8; ++mi)
      a += mean[(size_t)(j * 8 + mi) * ROW384 + t];
    atomicAdd(&Mc[t], a);
  } else {
    const int b = blk - (NJ_BLK + NM_BLK);
    if (t < 10) small[t] = betas[b * 10 + t];
    else if (t >= 10 && t < 19) small[t] = rot[b * 9 + (t - 10)];
    else if (t >= 19 && t < 22) small[t] = trans[b * 3 + (t - 19)];
    orgL[t] = org[(size_t)b * 384 + t];
    __syncthreads();
    // obj[n,d] -> X[b][0:384)
    {
      int n = t / 3, d = t % 3;
      X[(size_t)b * 2496 + t] =
          orgL[n * 3 + 0] * small[10 + d * 3 + 0] +
          orgL[n * 3 + 1] * small[10 + d * 3 + 1] +
          orgL[n * 3 + 2] * small[10 + d * 3 + 2] + small[19 + d];
    }
    // sa0[m,c] = vt + betas.sd (no J0) -> X[b][384:2496)
    float ps = 0.f;  // c = e%3 fixed per thread (384%3==0)
    for (int e = t; e < 2112; e += 384) {
      int m = e / 3, c = e - m * 3;
      int a = anch[m];
      const float* sp = sd + ((size_t)a * 3 + c) * KB;
      float val = vt[a * 3 + c];
#pragma unroll
      for (int k = 0; k < KB; ++k) val += small[k] * sp[k];
      X[(size_t)b * 2496 + 384 + e] = val;
      ps += val;
    }
    red[t] = ps;
    __syncthreads();
    if (t < 3) {
      float s = 0.f;
#pragma unroll 8
      for (int j = 0; j < 128; ++j) s += red[t + 3 * j];
      saSum[b * 3 + t] = s;
    }
  }
}

// ---------------------------------------------------------------- K2: single pass over pca_components
// block = (chunk, pid): 16x384 tile of pc row pid. All outputs contiguous per block:
//   Upart[chunk][pid][0:384]          = column sums over 16 m's (1536 B burst)
//   Wp[pid][384+m0*3 : 384+m0*3+48]   = -(row sums over n)      (192 B burst, exclusive)
//   cmean[pid]                       += tile . mean-tile        (1 atomic/block)
__global__ __launch_bounds__(384) void k_pcpass(
    const float* __restrict__ pc, const float* __restrict__ mean,
    float* __restrict__ Upart, float* __restrict__ Wp,
    float* __restrict__ cmean) {
  __shared__ float tile[MT * LSTR];  // 24,832 B
  __shared__ float red[384];
  __shared__ float cred[6];
  const int t = threadIdx.x;
  const int pid = blockIdx.x & 127;
  const int chunk = blockIdx.x >> 7;  // 0..43
  const int m0 = chunk * MT;
  const float* row = pc + (size_t)pid * D_TOT + (size_t)m0 * ROW384;
  const float* mrow = mean + (size_t)m0 * ROW384;

  float cm = 0.f;
#pragma unroll
  for (int i = 0; i < 4; ++i) {
    int f = 1536 * i + 4 * t;
    float4 pv = *(const float4*)(row + f);
    float4 mv = *(const float4*)(mrow + f);
    cm += pv.x * mv.x + pv.y * mv.y + pv.z * mv.z + pv.w * mv.w;
    int m_l = 4 * i + t / 96;
    int col = (t % 96) * 4;
    *(float4*)(&tile[m_l * LSTR + col]) = pv;
  }
  __syncthreads();  // S1

  // U partial: fixed (n,c)=t, sum over 16 m -> contiguous store
  {
    float u = 0.f;
#pragma unroll
    for (int m = 0; m < MT; ++m) u += tile[m * LSTR + t];
    Upart[((size_t)chunk * 128 + pid) * 384 + t] = u;
  }
  // V partial: t = grp*48 + (m_l*3+c), grp 0..7 each sums 16 n's
  {
    int grp = t / 48, mc = t % 48, m_l = mc / 3, c = mc % 3;
    const float* tp = &tile[m_l * LSTR + c];
    float vsp = 0.f;
#pragma unroll 8
    for (int j = 0; j < 16; ++j) vsp += tp[(grp * 16 + j) * 3];
    red[t] = vsp;
  }
  // cmean wave-reduce
  {
    float x = cm;
    for (int off = 32; off > 0; off >>= 1) x += __shfl_down(x, off);
    if ((t & 63) == 0) cred[t >> 6] = x;
  }
  __syncthreads();  // S2
  if (t < 48) {
    float vs = 0.f;
#pragma unroll
    for (int g = 0; g < 8; ++g) vs += red[g * 48 + t];
    Wp[(size_t)pid * 2496 + 384 + m0 * 3 + t] = -vs;  // W row = -V2; contiguous, exclusive
  }
  if (t == 0) {
    float s = cred[0] + cred[1] + cred[2] + cred[3] + cred[4] + cred[5];
    atomicAdd(&cmean[pid], s);
  }
}

// ---------------------------------------------------------------- K2b: reduce Upart -> Wp U rows; V2c
__global__ __launch_bounds__(384) void k_red(
    const float* __restrict__ Upart, float* __restrict__ Wp,
    float* __restrict__ V2c) {
  __shared__ float red[384];
  const int pid = blockIdx.x, t = threadIdx.x;
  float u = 0.f;
#pragma unroll 4
  for (int c = 0; c < NCHUNK; ++c)
    u += Upart[((size_t)c * 128 + pid) * 384 + t];
  Wp[(size_t)pid * 2496 + t] = u;
  // V2c[c][pid] = sum_m V2 = -(sum of Wp's V2 rows); thread t covers idx t+384j (c = t%3 fixed)
  float s = 0.f;
  const float* vr = Wp + (size_t)pid * 2496 + 384;
#pragma unroll
  for (int j = 0; j < 6; ++j) {
    int idx = t + 384 * j;
    if (idx < 2112) s += vr[idx];
  }
  red[t] = s;
  __syncthreads();
  if (t < 3) {
    float acc = 0.f;
#pragma unroll 8
    for (int j = 0; j < 128; ++j) acc += red[t + 3 * j];
    V2c[t * 128 + pid] = -acc;
  }
}

// ---------------------------------------------------------------- K3: gamma -- one WAVE per (b,p) dot
// gWS[b][p] = X[b][:] . Wp[p][:]  (both rows e-contiguous, float4 loads, L2-resident)
// grid = 64 b * 32 pgroups; wave w of the block handles p = pg*4 + w.
__global__ __launch_bounds__(256) void k_gamma(
    const float* __restrict__ X, const float* __restrict__ Wp,
    float* __restrict__ gWS) {
  const int t = threadIdx.x;
  const int b = blockIdx.x >> 5, pg = blockIdx.x & 31;
  const int w = t >> 6, l = t & 63;
  const int p = pg * 4 + w;
  const float4* X4 = (const float4*)(X + (size_t)b * 2496);
  const float4* W4 = (const float4*)(Wp + (size_t)p * 2496);
  float s = 0.f;
#pragma unroll
  for (int i = 0; i < 10; ++i) {
    int idx = i * 64 + l;
    if (idx < 624) {  // 2496/4
      float4 xv = X4[idx];
      float4 wv = W4[idx];
      s += xv.x * wv.x + xv.y * wv.y + xv.z * wv.z + xv.w * wv.w;
    }
  }
#pragma unroll
  for (int off = 32; off > 0; off >>= 1) s += __shfl_down(s, off);
  if (l == 0) gWS[b * 128 + p] = s;
}

// ---------------------------------------------------------------- 3x3 SVD -> rotation (Kabsch w/ reflection fix)
__device__ inline double det3(const double A[3][3]) {
  return A[0][0] * (A[1][1] * A[2][2] - A[1][2] * A[2][1])
       - A[0][1] * (A[1][0] * A[2][2] - A[1][2] * A[2][0])
       + A[0][2] * (A[1][0] * A[2][1] - A[1][1] * A[2][0]);
}

__device__ void svd3_rotation(const float* S, float* Rout) {
  double M[3][3], B[3][3], Vv[3][3];
  for (int i = 0; i < 3; ++i)
    for (int j = 0; j < 3; ++j) M[i][j] = (double)S[i * 3 + j];
  for (int i = 0; i < 3; ++i)
    for (int j = 0; j < 3; ++j) {
      double a = 0;
      for (int k = 0; k < 3; ++k) a += M[k][i] * M[k][j];
      B[i][j] = a;
    }
  for (int i = 0; i < 3; ++i)
    for (int j = 0; j < 3; ++j) Vv[i][j] = (i == j) ? 1.0 : 0.0;
  const int PP[3] = {0, 0, 1}, QQ[3] = {1, 2, 2};
  for (int sweep = 0; sweep < 25; ++sweep) {
    double off = B[0][1] * B[0][1] + B[0][2] * B[0][2] + B[1][2] * B[1][2];
    double dg = B[0][0] * B[0][0] + B[1][1] * B[1][1] + B[2][2] * B[2][2];
    if (off <= 1e-28 * (dg + 1e-300)) break;
    for (int pr = 0; pr < 3; ++pr) {
      int p = PP[pr], q = QQ[pr];
      double apq = B[p][q];
      if (apq == 0.0) continue;
      double dd = (B[p][p] - B[q][q]) / (2.0 * apq);
      double tt = 1.0 / (fabs(dd) + sqrt(dd * dd + 1.0));
      if (dd < 0.0) tt = -tt;
      double cc = 1.0 / sqrt(tt * tt + 1.0), ss = tt * cc;
      B[p][p] += tt * apq;
      B[q][q] -= tt * apq;
      B[p][q] = B[q][p] = 0.0;
      int k = 3 - p - q;
      double Bkp = cc * B[k][p] + ss * B[k][q];
      double Bkq = -ss * B[k][p] + cc * B[k][q];
      B[k][p] = B[p][k] = Bkp;
      B[k][q] = B[q][k] = Bkq;
      for (int i = 0; i < 3; ++i) {
        double vip = cc * Vv[i][p] + ss * Vv[i][q];
        double viq = -ss * Vv[i][p] + cc * Vv[i][q];
        Vv[i][p] = vip;
        Vv[i][q] = viq;
      }
    }
  }
  double lam[3] = {B[0][0], B[1][1], B[2][2]};
  int o0 = 0, o1 = 1, o2 = 2, tp;
  if (lam[o0] < lam[o1]) { tp = o0; o0 = o1; o1 = tp; }
  if (lam[o0] < lam[o2]) { tp = o0; o0 = o2; o2 = tp; }
  if (lam[o1] < lam[o2]) { tp = o1; o1 = o2; o2 = tp; }
  int ord[3] = {o0, o1, o2};
  double sv[3], U[3][3], Vs[3][3];
  for (int j = 0; j < 3; ++j) {
    double l = lam[ord[j]];
    sv[j] = l > 0.0 ? sqrt(l) : 0.0;
    for (int i = 0; i < 3; ++i) Vs[i][j] = Vv[i][ord[j]];
  }
  for (int j = 0; j < 3; ++j) {
    double vx = Vs[0][j], vy = Vs[1][j], vz = Vs[2][j];
    double ux = M[0][0] * vx + M[0][1] * vy + M[0][2] * vz;
    double uy = M[1][0] * vx + M[1][1] * vy + M[1][2] * vz;
    double uz = M[2][0] * vx + M[2][1] * vy + M[2][2] * vz;
    double sj = sv[j];
    if (sj > 1e-12 * (sv[0] + 1e-300)) {
      U[0][j] = ux / sj; U[1][j] = uy / sj; U[2][j] = uz / sj;
    } else if (j == 2) {
      double cx = U[1][0] * U[2][1] - U[2][0] * U[1][1];
      double cy = U[2][0] * U[0][1] - U[0][0] * U[2][1];
      double cz = U[0][0] * U[1][1] - U[1][0] * U[0][1];
      double nn = sqrt(cx * cx + cy * cy + cz * cz);
      if (nn < 1e-300) { cx = 0; cy = 0; cz = 1; nn = 1; }
      U[0][2] = cx / nn; U[1][2] = cy / nn; U[2][2] = cz / nn;
    } else {
      U[0][j] = (j == 0) ? 1.0 : 0.0;
      U[1][j] = (j == 1) ? 1.0 : 0.0;
      U[2][j] = 0.0;
    }
  }
  double dsgn = (det3(U) * det3(Vs)) < 0.0 ? -1.0 : 1.0;
  for (int i = 0; i < 3; ++i)
    for (int j = 0; j < 3; ++j)
      Rout[i * 3 + j] = (float)(U[i][0] * Vs[j][0] + U[i][1] * Vs[j][1] +
                                dsgn * U[i][2] * Vs[j][2]);
}

// ---------------------------------------------------------------- K4: finalize per batch
__global__ __launch_bounds__(384) void k_finish(
    const float* __restrict__ betas, const float* __restrict__ org,
    const float* __restrict__ JJ, const float* __restrict__ cmean,
    const float* __restrict__ Mc, const float* __restrict__ V2c,
    const float* __restrict__ saSum, const float* __restrict__ gWS,
    const float* __restrict__ Wp, float* __restrict__ out) {
  const int b = blockIdx.x, t = threadIdx.x;
  __shared__ float orgL[384], A[384], gammaL[128];
  __shared__ float betasL[10], J0L[3], cQ[3], smat[9], RL[9];

  if (t < 10) betasL[t] = betas[b * 10 + t];
  orgL[t] = org[(size_t)b * 384 + t];
  __syncthreads();
  if (t < 3) {
    float j0 = JJ[t];
#pragma unroll
    for (int k = 0; k < KB; ++k) j0 += betasL[k] * JJ[3 + t * KB + k];
    J0L[t] = j0;
    float s = 0.f;
    for (int n = 0; n < N_A; ++n) s += orgL[n * 3 + t];
    cQ[t] = s * (1.f / 128.f);
  }
  __syncthreads();

  // gamma finalize: + J0.V2c (restores the -J0 part of sa) - cmean
  if (t < 128) {
    float g = gWS[b * 128 + t] + J0L[0] * V2c[t] + J0L[1] * V2c[128 + t] +
              J0L[2] * V2c[256 + t] - cmean[t];
    gammaL[t] = g;
    out[b * 128 + t] = g;  // output 0
  }
  __syncthreads();

  // A[n,c] = Mc + sum_p gamma[p]*Wp[p][nc]  (U rows of Wp; coalesced over t)
  {
    float gs = 0.f;
#pragma unroll 4
    for (int p = 0; p < 128; ++p) gs += gammaL[p] * Wp[(size_t)p * 2496 + t];
    A[t] = Mc[t] + gs;
  }
  __syncthreads();

  if (t < 9) {
    int c = t / 3, d = t % 3;
    float s = 0.f, cq = cQ[d];
    for (int n = 0; n < N_A; ++n) s += A[n * 3 + c] * (orgL[n * 3 + d] - cq);
    smat[t] = s;
  }
  __syncthreads();
  if (t == 0) svd3_rotation(smat, RL);
  __syncthreads();
  if (t < 9) out[8192 + b * 9 + t] = RL[t];  // output 1
  if (t < 3) {
    float s2 = 0.f;
    for (int n = 0; n < N_A; ++n) s2 += A[n * 3 + t];
    float meanP = saSum[b * 3 + t] * (1.f / 704.f) - J0L[t] + s2 * (1.f / 90112.f);
    float rq = RL[t * 3 + 0] * cQ[0] + RL[t * 3 + 1] * cQ[1] + RL[t * 3 + 2] * cQ[2];
    out[8768 + b * 3 + t] = meanP - rq;  // output 2
  }
}

// ----------------------------------------------------------------
extern "C" void kernel_launch(void* const* d_in, const int* in_sizes, int n_in,
                              void* d_out, int out_size, void* d_ws, size_t ws_size,
                              hipStream_t stream) {
  const float* betas = (const float*)d_in[0];
  const float* rot   = (const float*)d_in[1];
  const float* trans = (const float*)d_in[2];
  const float* org   = (const float*)d_in[3];
  const float* vt    = (const float*)d_in[4];
  const float* sd    = (const float*)d_in[5];
  const float* Jr    = (const float*)d_in[6];
  const float* mean  = (const float*)d_in[7];
  const float* pc    = (const float*)d_in[8];
  const int*   anch  = (const int*)d_in[9];
  float* out = (float*)d_out;
  float* ws  = (float*)d_ws;
  if (ws_size < (size_t)WS_TOTAL * sizeof(float)) return;  // need ~10.6 MB scratch

  float* JJ    = ws + WS_JJ;
  float* cmean = ws + WS_CMEAN;
  float* Mc    = ws + WS_MC;
  float* V2c   = ws + WS_V2C;
  float* saSum = ws + WS_SASUM;
  float* gWS   = ws + WS_GWS;
  float* X     = ws + WS_X;
  float* Wp    = ws + WS_WP;
  float* Upart = ws + WS_UPART;

  hipMemsetAsync(ws, 0, (size_t)WS_ZEROF * sizeof(float), stream);
  k_pre<<<NJ_BLK + NM_BLK + NP_BLK, 384, 0, stream>>>(
      Jr, vt, sd, mean, betas, rot, trans, org, anch, JJ, Mc, X, saSum);
  k_pcpass<<<NCHUNK * 128, 384, 0, stream>>>(pc, mean, Upart, Wp, cmean);
  k_red<<<128, 384, 0, stream>>>(Upart, Wp, V2c);
  k_gamma<<<64 * 32, 256, 0, stream>>>(X, Wp, gWS);
  k_finish<<<64, 384, 0, stream>>>(betas, org, JJ, cmean, Mc, V2c, saSum, gWS,
                                   Wp, out);
}

// Round 7
// 264.465 us; speedup vs baseline: 1.7717x; 1.1554x over previous
//
#include <hip/hip_runtime.h>

// Problem constants
#define V_CNT   10475
#define M_A     704
#define N_A     128
#define KB      10
#define D_TOT   270336       // 704*128*3
#define ROW384  384          // 128*3 floats per m-row of a pc row
#define NCHUNK  44           // 704 / MT
#define MT      16           // m-tile in k_pcpass (24.8 KB LDS -> 5 blocks/CU)
#define LSTR    388          // LDS row stride: 388%32=4 breaks bank conflicts, %4==0 keeps float4 alignment

// ws layout (float offsets) -- NO global atomics anywhere, so NO memset needed.
#define WS_JJP    0          // 28*33 = 924   JJpart[blk][33]
#define WS_JJ     960        // 33            (k_red blk 128)
#define WS_MCP    1024       // 88*384        Mcpart[blk][384]
#define WS_MC     34816      // 384           (k_red blk 129)
#define WS_CMP    35200      // 44*128        cmpart[chunk][pid]
#define WS_CMEAN  40832      // 128           (k_red)
#define WS_V2C    40960      // 3*128         (k_red)
#define WS_SAP    41344      // 64*4*3        sapart[b][slice][3]
#define WS_GWS    42112      // 64*128        raw gamma dots (k_gamma)
#define WS_X      50304      // 64*2496       X[b][e]: [obj(384); sa0(2112)]
#define WS_WP     210048     // 128*2496      Wp[p][e]: [0,384)=U (k_red), [384,2496)=-V2 (k_pcpass)
#define WS_UPART  529536     // 44*128*384    Upart[chunk][pid][nc]
#define WS_TOTAL  2692224    // floats (10.8 MB)

#define NJ_BLK 28
#define NM_BLK 88
#define NP_BLK 256           // 64 b * 4 slices

// ---------------------------------------------------------------- K1: fused precompute
// blocks [0,28): J-reduce partials; [28,116): Mc partials; [116,372): per-b prep (4 slices/b)
__global__ __launch_bounds__(384) void k_pre(
    const float* __restrict__ Jr, const float* __restrict__ vt,
    const float* __restrict__ sd, const float* __restrict__ mean,
    const float* __restrict__ betas, const float* __restrict__ rot,
    const float* __restrict__ trans, const float* __restrict__ org,
    const int* __restrict__ anch,
    float* __restrict__ JJpart, float* __restrict__ Mcpart,
    float* __restrict__ X, float* __restrict__ sapart) {
  __shared__ float orgL[384];
  __shared__ float red[384];
  __shared__ float small[24];  // 0..9 betas, 10..18 rot, 19..21 trans
  __shared__ float jjs[33];
  const int blk = blockIdx.x, t = threadIdx.x;

  if (blk < NJ_BLK) {
    if (t < 33) jjs[t] = 0.f;
    __syncthreads();
    float acc[33];
#pragma unroll
    for (int i = 0; i < 33; ++i) acc[i] = 0.f;
    int v = blk * 384 + t;
    if (v < V_CNT) {
      float jr = Jr[v];
#pragma unroll
      for (int c = 0; c < 3; ++c) {
        acc[c] += jr * vt[v * 3 + c];
        const float* sp = sd + ((size_t)v * 3 + c) * KB;
#pragma unroll
        for (int k = 0; k < KB; ++k) acc[3 + c * KB + k] += jr * sp[k];
      }
    }
#pragma unroll
    for (int i = 0; i < 33; ++i) {
      float x = acc[i];
      for (int off = 32; off > 0; off >>= 1) x += __shfl_down(x, off);
      if ((t & 63) == 0) atomicAdd(&jjs[i], x);  // LDS atomic (fast, no global)
    }
    __syncthreads();
    if (t < 33) JJpart[blk * 33 + t] = jjs[t];
  } else if (blk < NJ_BLK + NM_BLK) {
    int j = blk - NJ_BLK;
    float a = 0.f;
#pragma unroll
    for (int mi = 0; mi < 8; ++mi)
      a += mean[(size_t)(j * 8 + mi) * ROW384 + t];
    Mcpart[(size_t)j * 384 + t] = a;
  } else {
    // per-batch prep: b = idx/4; slice sl owns sa elements [sl*528, sl*528+528)
    const int idx = blk - (NJ_BLK + NM_BLK);
    const int b = idx >> 2, sl = idx & 3;
    if (t < 10) small[t] = betas[b * 10 + t];
    else if (t >= 10 && t < 19) small[t] = rot[b * 9 + (t - 10)];
    else if (t >= 19 && t < 22) small[t] = trans[b * 3 + (t - 19)];
    if (sl == 0) orgL[t] = org[(size_t)b * 384 + t];
    __syncthreads();
    if (sl == 0) {
      // obj[n,d] -> X[b][0:384)
      int n = t / 3, d = t % 3;
      X[(size_t)b * 2496 + t] =
          orgL[n * 3 + 0] * small[10 + d * 3 + 0] +
          orgL[n * 3 + 1] * small[10 + d * 3 + 1] +
          orgL[n * 3 + 2] * small[10 + d * 3 + 2] + small[19 + d];
    }
    // sa0[m,c] = vt + betas.sd (no J0) -> X[b][384:2496)
    float ps = 0.f;  // c = e%3 fixed per thread (384%3==0, 528%3==0)
#pragma unroll
    for (int r = 0; r < 2; ++r) {
      int el = t + r * 384;
      if (el < 528) {
        int e = sl * 528 + el;
        int m = e / 3, c = e - m * 3;
        int a = anch[m];
        const float* sp = sd + ((size_t)a * 3 + c) * KB;
        float val = vt[a * 3 + c];
#pragma unroll
        for (int k = 0; k < KB; ++k) val += small[k] * sp[k];
        X[(size_t)b * 2496 + 384 + e] = val;
        ps += val;
      }
    }
    red[t] = ps;
    __syncthreads();
    if (t < 3) {
      float s = 0.f;
#pragma unroll 8
      for (int j = 0; j < 128; ++j) s += red[t + 3 * j];
      sapart[idx * 3 + t] = s;  // private slot, no atomic
    }
  }
}

// ---------------------------------------------------------------- K2: single pass over pca_components
// block = (chunk, pid): 16x384 tile of pc row pid. All outputs contiguous/private:
//   Upart[chunk][pid][0:384]          = column sums over 16 m's
//   Wp[pid][384+m0*3 : +48]           = -(row sums over n)
//   cmpart[chunk][pid]                = tile . mean-tile
__global__ __launch_bounds__(384) void k_pcpass(
    const float* __restrict__ pc, const float* __restrict__ mean,
    float* __restrict__ Upart, float* __restrict__ Wp,
    float* __restrict__ cmpart) {
  __shared__ float tile[MT * LSTR];  // 24,832 B
  __shared__ float red[384];
  __shared__ float cred[6];
  const int t = threadIdx.x;
  const int pid = blockIdx.x & 127;
  const int chunk = blockIdx.x >> 7;  // 0..43
  const int m0 = chunk * MT;
  const float* row = pc + (size_t)pid * D_TOT + (size_t)m0 * ROW384;
  const float* mrow = mean + (size_t)m0 * ROW384;

  float cm = 0.f;
#pragma unroll
  for (int i = 0; i < 4; ++i) {
    int f = 1536 * i + 4 * t;
    float4 pv = *(const float4*)(row + f);
    float4 mv = *(const float4*)(mrow + f);
    cm += pv.x * mv.x + pv.y * mv.y + pv.z * mv.z + pv.w * mv.w;
    int m_l = 4 * i + t / 96;
    int col = (t % 96) * 4;
    *(float4*)(&tile[m_l * LSTR + col]) = pv;
  }
  __syncthreads();  // S1

  // U partial: fixed (n,c)=t, sum over 16 m -> contiguous store
  {
    float u = 0.f;
#pragma unroll
    for (int m = 0; m < MT; ++m) u += tile[m * LSTR + t];
    Upart[((size_t)chunk * 128 + pid) * 384 + t] = u;
  }
  // V partial: t = grp*48 + (m_l*3+c), grp 0..7 each sums 16 n's
  {
    int grp = t / 48, mc = t % 48, m_l = mc / 3, c = mc % 3;
    const float* tp = &tile[m_l * LSTR + c];
    float vsp = 0.f;
#pragma unroll 8
    for (int j = 0; j < 16; ++j) vsp += tp[(grp * 16 + j) * 3];
    red[t] = vsp;
  }
  // cmean wave-reduce
  {
    float x = cm;
    for (int off = 32; off > 0; off >>= 1) x += __shfl_down(x, off);
    if ((t & 63) == 0) cred[t >> 6] = x;
  }
  __syncthreads();  // S2
  if (t < 48) {
    float vs = 0.f;
#pragma unroll
    for (int g = 0; g < 8; ++g) vs += red[g * 48 + t];
    Wp[(size_t)pid * 2496 + 384 + m0 * 3 + t] = -vs;  // W row = -V2; contiguous, exclusive
  }
  if (t == 0)
    cmpart[chunk * 128 + pid] =
        cred[0] + cred[1] + cred[2] + cred[3] + cred[4] + cred[5];
}

// ---------------------------------------------------------------- K2b: all reductions (no atomics)
// blocks [0,128): per-pid (Upart->Wp U rows, V2c, cmean); 128: JJ; 129: Mc
__global__ __launch_bounds__(384) void k_red(
    const float* __restrict__ Upart, const float* __restrict__ JJpart,
    const float* __restrict__ Mcpart, const float* __restrict__ cmpart,
    float* __restrict__ Wp, float* __restrict__ V2c,
    float* __restrict__ JJ, float* __restrict__ Mc,
    float* __restrict__ cmean) {
  const int t = threadIdx.x;
  if (blockIdx.x == 128) {
    if (t < 33) {
      float s = 0.f;
#pragma unroll 4
      for (int j = 0; j < NJ_BLK; ++j) s += JJpart[j * 33 + t];
      JJ[t] = s;
    }
    return;
  }
  if (blockIdx.x == 129) {
    float s = 0.f;
#pragma unroll 4
    for (int j = 0; j < NM_BLK; ++j) s += Mcpart[(size_t)j * 384 + t];
    Mc[t] = s;
    return;
  }
  __shared__ float red[384];
  const int pid = blockIdx.x;
  float u = 0.f;
#pragma unroll 4
  for (int c = 0; c < NCHUNK; ++c)
    u += Upart[((size_t)c * 128 + pid) * 384 + t];
  Wp[(size_t)pid * 2496 + t] = u;
  // V2c[c][pid] = sum_m V2 = -(sum of Wp's -V2 rows); thread t covers idx t+384j (c = t%3 fixed)
  float s = 0.f;
  const float* vr = Wp + (size_t)pid * 2496 + 384;
#pragma unroll
  for (int j = 0; j < 6; ++j) {
    int idx = t + 384 * j;
    if (idx < 2112) s += vr[idx];
  }
  red[t] = s;
  // cmean[pid] = sum_chunk cmpart (wave 0)
  if (t < 64) {
    float x = (t < NCHUNK) ? cmpart[t * 128 + pid] : 0.f;
#pragma unroll
    for (int off = 32; off > 0; off >>= 1) x += __shfl_down(x, off);
    if (t == 0) cmean[pid] = x;
  }
  __syncthreads();
  if (t < 3) {
    float acc = 0.f;
#pragma unroll 8
    for (int j = 0; j < 128; ++j) acc += red[t + 3 * j];
    V2c[t * 128 + pid] = -acc;
  }
}

// ---------------------------------------------------------------- K3: gamma -- one WAVE per (b,p) dot
__global__ __launch_bounds__(256) void k_gamma(
    const float* __restrict__ X, const float* __restrict__ Wp,
    float* __restrict__ gWS) {
  const int t = threadIdx.x;
  const int b = blockIdx.x >> 5, pg = blockIdx.x & 31;
  const int w = t >> 6, l = t & 63;
  const int p = pg * 4 + w;
  const float4* X4 = (const float4*)(X + (size_t)b * 2496);
  const float4* W4 = (const float4*)(Wp + (size_t)p * 2496);
  float s = 0.f;
#pragma unroll
  for (int i = 0; i < 10; ++i) {
    int idx = i * 64 + l;
    if (idx < 624) {  // 2496/4
      float4 xv = X4[idx];
      float4 wv = W4[idx];
      s += xv.x * wv.x + xv.y * wv.y + xv.z * wv.z + xv.w * wv.w;
    }
  }
#pragma unroll
  for (int off = 32; off > 0; off >>= 1) s += __shfl_down(s, off);
  if (l == 0) gWS[b * 128 + p] = s;
}

// ---------------------------------------------------------------- 3x3 SVD -> rotation (Kabsch w/ reflection fix)
__device__ inline double det3(const double A[3][3]) {
  return A[0][0] * (A[1][1] * A[2][2] - A[1][2] * A[2][1])
       - A[0][1] * (A[1][0] * A[2][2] - A[1][2] * A[2][0])
       + A[0][2] * (A[1][0] * A[2][1] - A[1][1] * A[2][0]);
}

__device__ void svd3_rotation(const float* S, float* Rout) {
  double M[3][3], B[3][3], Vv[3][3];
  for (int i = 0; i < 3; ++i)
    for (int j = 0; j < 3; ++j) M[i][j] = (double)S[i * 3 + j];
  for (int i = 0; i < 3; ++i)
    for (int j = 0; j < 3; ++j) {
      double a = 0;
      for (int k = 0; k < 3; ++k) a += M[k][i] * M[k][j];
      B[i][j] = a;
    }
  for (int i = 0; i < 3; ++i)
    for (int j = 0; j < 3; ++j) Vv[i][j] = (i == j) ? 1.0 : 0.0;
  const int PP[3] = {0, 0, 1}, QQ[3] = {1, 2, 2};
  for (int sweep = 0; sweep < 25; ++sweep) {
    double off = B[0][1] * B[0][1] + B[0][2] * B[0][2] + B[1][2] * B[1][2];
    double dg = B[0][0] * B[0][0] + B[1][1] * B[1][1] + B[2][2] * B[2][2];
    if (off <= 1e-28 * (dg + 1e-300)) break;
    for (int pr = 0; pr < 3; ++pr) {
      int p = PP[pr], q = QQ[pr];
      double apq = B[p][q];
      if (apq == 0.0) continue;
      double dd = (B[p][p] - B[q][q]) / (2.0 * apq);
      double tt = 1.0 / (fabs(dd) + sqrt(dd * dd + 1.0));
      if (dd < 0.0) tt = -tt;
      double cc = 1.0 / sqrt(tt * tt + 1.0), ss = tt * cc;
      B[p][p] += tt * apq;
      B[q][q] -= tt * apq;
      B[p][q] = B[q][p] = 0.0;
      int k = 3 - p - q;
      double Bkp = cc * B[k][p] + ss * B[k][q];
      double Bkq = -ss * B[k][p] + cc * B[k][q];
      B[k][p] = B[p][k] = Bkp;
      B[k][q] = B[q][k] = Bkq;
      for (int i = 0; i < 3; ++i) {
        double vip = cc * Vv[i][p] + ss * Vv[i][q];
        double viq = -ss * Vv[i][p] + cc * Vv[i][q];
        Vv[i][p] = vip;
        Vv[i][q] = viq;
      }
    }
  }
  double lam[3] = {B[0][0], B[1][1], B[2][2]};
  int o0 = 0, o1 = 1, o2 = 2, tp;
  if (lam[o0] < lam[o1]) { tp = o0; o0 = o1; o1 = tp; }
  if (lam[o0] < lam[o2]) { tp = o0; o0 = o2; o2 = tp; }
  if (lam[o1] < lam[o2]) { tp = o1; o1 = o2; o2 = tp; }
  int ord[3] = {o0, o1, o2};
  double sv[3], U[3][3], Vs[3][3];
  for (int j = 0; j < 3; ++j) {
    double l = lam[ord[j]];
    sv[j] = l > 0.0 ? sqrt(l) : 0.0;
    for (int i = 0; i < 3; ++i) Vs[i][j] = Vv[i][ord[j]];
  }
  for (int j = 0; j < 3; ++j) {
    double vx = Vs[0][j], vy = Vs[1][j], vz = Vs[2][j];
    double ux = M[0][0] * vx + M[0][1] * vy + M[0][2] * vz;
    double uy = M[1][0] * vx + M[1][1] * vy + M[1][2] * vz;
    double uz = M[2][0] * vx + M[2][1] * vy + M[2][2] * vz;
    double sj = sv[j];
    if (sj > 1e-12 * (sv[0] + 1e-300)) {
      U[0][j] = ux / sj; U[1][j] = uy / sj; U[2][j] = uz / sj;
    } else if (j == 2) {
      double cx = U[1][0] * U[2][1] - U[2][0] * U[1][1];
      double cy = U[2][0] * U[0][1] - U[0][0] * U[2][1];
      double cz = U[0][0] * U[1][1] - U[1][0] * U[0][1];
      double nn = sqrt(cx * cx + cy * cy + cz * cz);
      if (nn < 1e-300) { cx = 0; cy = 0; cz = 1; nn = 1; }
      U[0][2] = cx / nn; U[1][2] = cy / nn; U[2][2] = cz / nn;
    } else {
      U[0][j] = (j == 0) ? 1.0 : 0.0;
      U[1][j] = (j == 1) ? 1.0 : 0.0;
      U[2][j] = 0.0;
    }
  }
  double dsgn = (det3(U) * det3(Vs)) < 0.0 ? -1.0 : 1.0;
  for (int i = 0; i < 3; ++i)
    for (int j = 0; j < 3; ++j)
      Rout[i * 3 + j] = (float)(U[i][0] * Vs[j][0] + U[i][1] * Vs[j][1] +
                                dsgn * U[i][2] * Vs[j][2]);
}

// ---------------------------------------------------------------- K4: finalize per batch
__global__ __launch_bounds__(384) void k_finish(
    const float* __restrict__ betas, const float* __restrict__ org,
    const float* __restrict__ JJ, const float* __restrict__ cmean,
    const float* __restrict__ Mc, const float* __restrict__ V2c,
    const float* __restrict__ sapart, const float* __restrict__ gWS,
    const float* __restrict__ Wp, float* __restrict__ out) {
  const int b = blockIdx.x, t = threadIdx.x;
  __shared__ float orgL[384];
  __shared__ __align__(16) float A[384];
  __shared__ float gammaL[128];
  __shared__ float betasL[10], J0L[3], cQ[3], smat[9], RL[9];

  if (t < 10) betasL[t] = betas[b * 10 + t];
  orgL[t] = org[(size_t)b * 384 + t];
  __syncthreads();
  if (t < 3) {
    float j0 = JJ[t];
#pragma unroll
    for (int k = 0; k < KB; ++k) j0 += betasL[k] * JJ[3 + t * KB + k];
    J0L[t] = j0;
    float s = 0.f;
    for (int n = 0; n < N_A; ++n) s += orgL[n * 3 + t];
    cQ[t] = s * (1.f / 128.f);
  }
  __syncthreads();

  // gamma finalize: + J0.V2c (restores the -J0 part of sa) - cmean
  if (t < 128) {
    float g = gWS[b * 128 + t] + J0L[0] * V2c[t] + J0L[1] * V2c[128 + t] +
              J0L[2] * V2c[256 + t] - cmean[t];
    gammaL[t] = g;
    out[b * 128 + t] = g;  // output 0
  }
  __syncthreads();

  // A[nc] = Mc + sum_p gamma[p]*Wp[p][nc]  (float4: threads 0..95 cover 384 nc)
  if (t < 96) {
    float4 gs = {0.f, 0.f, 0.f, 0.f};
#pragma unroll 4
    for (int p = 0; p < 128; ++p) {
      float4 w = *(const float4*)(Wp + (size_t)p * 2496 + 4 * t);
      float g = gammaL[p];
      gs.x += g * w.x; gs.y += g * w.y; gs.z += g * w.z; gs.w += g * w.w;
    }
    float4 m4 = *(const float4*)(Mc + 4 * t);
    float4 a4 = {m4.x + gs.x, m4.y + gs.y, m4.z + gs.z, m4.w + gs.w};
    *(float4*)(&A[4 * t]) = a4;
  }
  __syncthreads();

  if (t < 9) {
    int c = t / 3, d = t % 3;
    float s = 0.f, cq = cQ[d];
    for (int n = 0; n < N_A; ++n) s += A[n * 3 + c] * (orgL[n * 3 + d] - cq);
    smat[t] = s;
  }
  __syncthreads();
  if (t == 0) svd3_rotation(smat, RL);
  __syncthreads();
  if (t < 9) out[8192 + b * 9 + t] = RL[t];  // output 1
  if (t < 3) {
    float sSum = sapart[(b * 4 + 0) * 3 + t] + sapart[(b * 4 + 1) * 3 + t] +
                 sapart[(b * 4 + 2) * 3 + t] + sapart[(b * 4 + 3) * 3 + t];
    float s2 = 0.f;
    for (int n = 0; n < N_A; ++n) s2 += A[n * 3 + t];
    float meanP = sSum * (1.f / 704.f) - J0L[t] + s2 * (1.f / 90112.f);
    float rq = RL[t * 3 + 0] * cQ[0] + RL[t * 3 + 1] * cQ[1] + RL[t * 3 + 2] * cQ[2];
    out[8768 + b * 3 + t] = meanP - rq;  // output 2
  }
}

// ----------------------------------------------------------------
extern "C" void kernel_launch(void* const* d_in, const int* in_sizes, int n_in,
                              void* d_out, int out_size, void* d_ws, size_t ws_size,
                              hipStream_t stream) {
  const float* betas = (const float*)d_in[0];
  const float* rot   = (const float*)d_in[1];
  const float* trans = (const float*)d_in[2];
  const float* org   = (const float*)d_in[3];
  const float* vt    = (const float*)d_in[4];
  const float* sd    = (const float*)d_in[5];
  const float* Jr    = (const float*)d_in[6];
  const float* mean  = (const float*)d_in[7];
  const float* pc    = (const float*)d_in[8];
  const int*   anch  = (const int*)d_in[9];
  float* out = (float*)d_out;
  float* ws  = (float*)d_ws;
  if (ws_size < (size_t)WS_TOTAL * sizeof(float)) return;  // need ~10.8 MB scratch

  float* JJpart = ws + WS_JJP;
  float* JJ     = ws + WS_JJ;
  float* Mcpart = ws + WS_MCP;
  float* Mc     = ws + WS_MC;
  float* cmpart = ws + WS_CMP;
  float* cmean  = ws + WS_CMEAN;
  float* V2c    = ws + WS_V2C;
  float* sapart = ws + WS_SAP;
  float* gWS    = ws + WS_GWS;
  float* X      = ws + WS_X;
  float* Wp     = ws + WS_WP;
  float* Upart  = ws + WS_UPART;

  k_pre<<<NJ_BLK + NM_BLK + NP_BLK, 384, 0, stream>>>(
      Jr, vt, sd, mean, betas, rot, trans, org, anch, JJpart, Mcpart, X, sapart);
  k_pcpass<<<NCHUNK * 128, 384, 0, stream>>>(pc, mean, Upart, Wp, cmpart);
  k_red<<<130, 384, 0, stream>>>(Upart, JJpart, Mcpart, cmpart, Wp, V2c, JJ, Mc,
                                 cmean);
  k_gamma<<<64 * 32, 256, 0, stream>>>(X, Wp, gWS);
  k_finish<<<64, 384, 0, stream>>>(betas, org, JJ, cmean, Mc, V2c, sapart, gWS,
                                   Wp, out);
}